// Round 1
// 2821.987 us; speedup vs baseline: 1.3279x; 1.3279x over previous
//
#include <hip/hip_runtime.h>
#include <stdint.h>

#define V_ 32000
#define E_ 512
#define H_ 1024
#define M_ 256
#define B_ 2
#define S_ 1024
#define GC_ 24

typedef unsigned short u16;
typedef unsigned int u32;
typedef unsigned long long u64;

typedef __attribute__((ext_vector_type(8))) short short8;
typedef __attribute__((ext_vector_type(4))) float floatx4;
typedef __attribute__((ext_vector_type(2))) float floatx2;
typedef __attribute__((ext_vector_type(2))) _Float16 halfx2;

__device__ __forceinline__ float bf2f(u16 u){ return __uint_as_float(((u32)u) << 16); }
__device__ __forceinline__ float bflo(u32 u){ return __uint_as_float(u << 16); }
__device__ __forceinline__ float bfhi(u32 u){ return __uint_as_float(u & 0xffff0000u); }
__device__ __forceinline__ u16 f2bf(float f){
  u32 u = __float_as_uint(f);
  u32 r = (u + 0x7fffu + ((u >> 16) & 1u)) >> 16;
  return (u16)r;
}
__device__ __forceinline__ float sigm(float x){ return 1.f / (1.f + __expf(-x)); }

// 2-wide f16 dot product accumulating into f32 (v_dot2_f32_f16); graceful fallback.
__device__ __forceinline__ float dot2f16(u32 a, u32 b, float c){
#if __has_builtin(__builtin_amdgcn_fdot2)
  return __builtin_amdgcn_fdot2(__builtin_bit_cast(halfx2, a),
                                __builtin_bit_cast(halfx2, b), c, false);
#else
  halfx2 av = __builtin_bit_cast(halfx2, a);
  halfx2 bv = __builtin_bit_cast(halfx2, b);
  return fmaf((float)av.y, (float)bv.y, fmaf((float)av.x, (float)bv.x, c));
#endif
}

// ---------------- dtype probe: low-u16-as-bf16 plausibility test on emb ----------------
__global__ __launch_bounds__(64) void detect_kernel(const u32* __restrict__ emb,
    int* __restrict__ flag, float* __restrict__ scal,
    const void* __restrict__ lam, const void* __restrict__ ms)
{
  int lane = threadIdx.x;
  int c = 0;
  for (int i = lane; i < 256; i += 64){
    u32 w = emb[i];
    float a = fabsf(__uint_as_float((w & 0xffffu) << 16));
    if (a > 1e-5f && a < 1.0f) c++;
  }
  #pragma unroll
  for (int o = 32; o; o >>= 1) c += __shfl_down(c, o, 64);
  if (lane == 0){
    int isf32 = (c < 128) ? 1 : 0;
    *flag = isf32;
    if (isf32) scal[0] = ((const float*)lam)[0];
    else {
      float v = bf2f(((const u16*)lam)[0]);
      scal[0] = (fabsf(v) <= 4.0f) ? v : ((const float*)lam)[0];
    }
    if (isf32) scal[1] = ((const float*)ms)[0];
    else {
      u16 a = ((const u16*)ms)[0];
      float v = bf2f(a);
      scal[1] = (a != 0 && fabsf(v) > 1e-4f && fabsf(v) < 1e4f) ? v : ((const float*)ms)[0];
    }
  }
}

// ---------------- canonicalize any float input to bf16 ----------------
__global__ __launch_bounds__(256) void conv_kernel(const void* __restrict__ src,
    u16* __restrict__ dst, int n, const int* __restrict__ flag)
{
  int i = blockIdx.x * 256 + threadIdx.x;
  if (i >= n) return;
  if (*flag) dst[i] = f2bf(((const float*)src)[i]);
  else       dst[i] = ((const u16*)src)[i];
}

// ---------------- canonicalize to f16 (for GRU W_hh: used by v_dot2_f32_f16) ----------------
__global__ __launch_bounds__(256) void convh_kernel(const void* __restrict__ src,
    u16* __restrict__ dst, int n, const int* __restrict__ flag)
{
  int i = blockIdx.x * 256 + threadIdx.x;
  if (i >= n) return;
  float v = (*flag) ? ((const float*)src)[i] : bf2f(((const u16*)src)[i]);
  _Float16 h = (_Float16)v;
  dst[i] = __builtin_bit_cast(u16, h);
}

// ---------------- smear: x' = emb[ids]; x'[t] += lam*sigmoid(x[t,:24]@smW)*x[t-1] ----------------
__global__ __launch_bounds__(64) void smear_kernel(const int* __restrict__ ids,
    const u16* __restrict__ emb, const u16* __restrict__ smW,
    const float* __restrict__ scal, u16* __restrict__ xs)
{
  int row = blockIdx.x;                 // b*S + t
  int t = row & (S_ - 1);
  int lane = threadIdx.x;
  int id = ids[row];
  const u16* er = emb + (size_t)id * E_;
  float sg = 0.f;
  if (t > 0){
    float p = 0.f;
    if (lane < GC_) p = bf2f(er[lane]) * bf2f(smW[lane]);
    #pragma unroll
    for (int o = 32; o; o >>= 1) p += __shfl_down(p, o, 64);
    float dot = __shfl(p, 0, 64);
    sg = scal[0] * sigm(dot);
  }
  uint4 cur = ((const uint4*)er)[lane];
  uint4 outv = cur;
  if (t > 0){
    const u16* ep = emb + (size_t)ids[row - 1] * E_;
    uint4 prv = ((const uint4*)ep)[lane];
    const u16* cu = (const u16*)&cur;
    const u16* pu = (const u16*)&prv;
    u16* po = (u16*)&outv;
    #pragma unroll
    for (int j = 0; j < 8; j++) po[j] = f2bf(bf2f(cu[j]) + sg * bf2f(pu[j]));
  }
  ((uint4*)(xs + (size_t)row * E_))[lane] = outv;
}

// ---------------- generic MFMA GEMM: C(M,N) = A(M,K) * Bm(N,K)^T + bias(N) ----------------
template<bool OUT_BF16>
__global__ __launch_bounds__(256) void gemm_bt(
    const u16* __restrict__ A, const u16* __restrict__ Bm,
    const u16* __restrict__ bias, void* __restrict__ Cout,
    int K, int Ndim)
{
  int wave = threadIdx.x >> 6, lane = threadIdx.x & 63;
  int wm = wave >> 1, wn = wave & 1;
  int m0 = blockIdx.y * 128 + wm * 64;
  int n0 = blockIdx.x * 128 + wn * 64;
  int lrow = lane & 15, lq = lane >> 4;
  floatx4 acc[4][4];
  #pragma unroll
  for (int i = 0; i < 4; i++)
    #pragma unroll
    for (int j = 0; j < 4; j++) acc[i][j] = (floatx4)0.f;
  const u16* Ab = A + (size_t)(m0 + lrow) * K + lq * 8;
  const u16* Bb = Bm + (size_t)(n0 + lrow) * K + lq * 8;
  for (int k0 = 0; k0 < K; k0 += 32){
    short8 af[4], bfr[4];
    #pragma unroll
    for (int tt = 0; tt < 4; tt++)
      af[tt] = *(const short8*)(Ab + (size_t)tt * 16 * K + k0);
    #pragma unroll
    for (int tt = 0; tt < 4; tt++)
      bfr[tt] = *(const short8*)(Bb + (size_t)tt * 16 * K + k0);
    #pragma unroll
    for (int im = 0; im < 4; im++)
      #pragma unroll
      for (int in = 0; in < 4; in++)
        acc[im][in] = __builtin_amdgcn_mfma_f32_16x16x32_bf16(af[im], bfr[in], acc[im][in], 0, 0, 0);
  }
  #pragma unroll
  for (int in = 0; in < 4; in++){
    int n = n0 + in * 16 + lrow;
    float bv = bf2f(bias[n]);
    #pragma unroll
    for (int im = 0; im < 4; im++){
      int mb = m0 + im * 16 + lq * 4;
      #pragma unroll
      for (int r = 0; r < 4; r++){
        float v = acc[im][in][r] + bv;
        size_t off = (size_t)(mb + r) * Ndim + n;
        if (OUT_BF16) ((u16*)Cout)[off] = f2bf(v);
        else          ((float*)Cout)[off] = v;
      }
    }
  }
}

// ---------------- GRU persistent scan (64 WGs x 1024 thr, tag-in-data 2-slot sync) ----------------
// v2: f16 weights + v_dot2_f32_f16 inner loop, xg prefetch, double-buffered LDS staging
//     (2 barriers/step instead of 3), 512-thread x2-wide polling, fast tanh, setprio tail.
__global__ __launch_bounds__(1024) void gru_kernel(
    const float* __restrict__ xg, const u16* __restrict__ W_hh,
    const u16* __restrict__ b_hh, u64* __restrict__ hslot,
    u16* __restrict__ states)
{
  const int b = blockIdx.x >> 5;
  const int ibase = (blockIdx.x & 31) * 32;
  const int tid = threadIdx.x;
  const int kg = tid >> 5;     // k-chunk 0..31 (32 k each)
  const int il = tid & 31;     // output within slice
  const int i = ibase + il;
  const int w = tid >> 6;      // wave 0..15

  __shared__ float lds_h[2][H_];        // f32 h (tail blend)
  __shared__ u32   lds_hpk[2][H_ / 2];  // packed f16 pairs of h (dot2 operand)
  __shared__ float lds_xg[2][96];
  __shared__ float red[3][16][32];

  // resident weights: 3 gates x 32 k as f16 pairs (16 u32 each) = 48 VGPRs
  uint4 Wv[3][4];
  #pragma unroll
  for (int g = 0; g < 3; g++){
    const uint4* p = (const uint4*)(W_hh + ((size_t)(g * H_ + i)) * H_ + kg * 32);
    #pragma unroll
    for (int q = 0; q < 4; q++) Wv[g][q] = p[q];
  }
  float bh0 = bf2f(b_hh[i]);
  float bh1 = bf2f(b_hh[H_ + i]);
  float bh2 = bf2f(b_hh[2 * H_ + i]);

  // prefetch xg for t=0
  float xg_next = 0.f;
  if (tid < 96)
    xg_next = xg[((size_t)(b * S_)) * 3072 + (tid >> 5) * H_ + ibase + (tid & 31)];

  for (int t = 0; t < S_; t++){
    const int cur = t & 1;
    // ---- poll: 512 threads, 2 elements each (tag-in-data u64, ABA-safe ping-pong) ----
    if (tid < 512){
      const u64* rptr = hslot + ((size_t)((cur ^ 1) * B_ + b)) * H_ + 2 * tid;
      u64 u0, u1;
      do {
        u0 = __hip_atomic_load(rptr,     __ATOMIC_RELAXED, __HIP_MEMORY_SCOPE_AGENT);
        u1 = __hip_atomic_load(rptr + 1, __ATOMIC_RELAXED, __HIP_MEMORY_SCOPE_AGENT);
      } while (((u32)(u0 >> 32) != (u32)t) || ((u32)(u1 >> 32) != (u32)t));
      float h0 = __uint_as_float((u32)u0);
      float h1 = __uint_as_float((u32)u1);
      *(floatx2*)&lds_h[cur][2 * tid] = (floatx2){h0, h1};
      lds_hpk[cur][tid] = __builtin_bit_cast(u32, __builtin_amdgcn_cvt_pkrtz(h0, h1));
    }
    if (tid < 96) lds_xg[cur][tid] = xg_next;
    __syncthreads();
    // issue next step's xg load now — latency hides under compute+tail+poll
    if (tid < 96 && t + 1 < S_)
      xg_next = xg[((size_t)(b * S_ + t + 1)) * 3072 + (tid >> 5) * H_ + ibase + (tid & 31)];

    // ---- matvec partials: 48 x v_dot2_f32_f16 over this thread's 32-k chunk ----
    const u32* hp = &lds_hpk[cur][kg * 16];
    float pr = 0.f, pz = 0.f, pn = 0.f;
    #pragma unroll
    for (int q = 0; q < 4; q++){
      uint4 wr = Wv[0][q], wz = Wv[1][q], wn4 = Wv[2][q];
      u32 cr[4] = {wr.x, wr.y, wr.z, wr.w};
      u32 cz[4] = {wz.x, wz.y, wz.z, wz.w};
      u32 cn[4] = {wn4.x, wn4.y, wn4.z, wn4.w};
      #pragma unroll
      for (int e = 0; e < 4; e++){
        u32 h2 = hp[q * 4 + e];
        pr = dot2f16(cr[e], h2, pr);
        pz = dot2f16(cz[e], h2, pz);
        pn = dot2f16(cn[e], h2, pn);
      }
    }
    pr += __shfl_xor(pr, 32, 64);
    pz += __shfl_xor(pz, 32, 64);
    pn += __shfl_xor(pn, 32, 64);
    if ((tid & 63) < 32){
      red[0][w][il] = pr; red[1][w][il] = pz; red[2][w][il] = pn;
    }
    __syncthreads();
    // ---- tail: wave 0 finishes reduction, nonlinearity, publishes h_{t+1} ----
    if (tid < 32){
      __builtin_amdgcn_s_setprio(3);
      float hr = 0.f, hz = 0.f, hn = 0.f;
      #pragma unroll
      for (int ww = 0; ww < 16; ww++){
        hr += red[0][ww][tid]; hz += red[1][ww][tid]; hn += red[2][ww][tid];
      }
      float r = sigm(lds_xg[cur][tid] + hr + bh0);
      float z = sigm(lds_xg[cur][32 + tid] + hz + bh1);
      float xx = lds_xg[cur][64 + tid] + r * (hn + bh2);
      float ax = fabsf(xx);
      float et = __expf(-2.f * ax);                       // overflow-safe fast tanh
      float n = copysignf((1.f - et) * __builtin_amdgcn_rcpf(1.f + et), xx);
      float ho = lds_h[cur][ibase + tid];
      float hnew = (1.f - z) * n + z * ho;
      u64 pk = (((u64)(u32)(t + 1)) << 32) | (u64)__float_as_uint(hnew);
      __hip_atomic_store(hslot + ((size_t)(cur * B_ + b)) * H_ + ibase + tid, pk,
                         __ATOMIC_RELAXED, __HIP_MEMORY_SCOPE_AGENT);
      states[((size_t)(b * S_ + t)) * H_ + ibase + tid] = f2bf(hnew);
      __builtin_amdgcn_s_setprio(0);
    }
    // no end-of-loop barrier: staging buffers are double-buffered by (t&1); the
    // next step's stage-barrier can't complete until wave 0 finishes this tail.
  }
}

// ---------------- g gate: sigmoid(states @ Wg + bg) ----------------
__global__ __launch_bounds__(256) void gk_kernel(const u16* __restrict__ states,
    const u16* __restrict__ Wg, const u16* __restrict__ bg, float* __restrict__ gws)
{
  int row = blockIdx.x * 4 + (threadIdx.x >> 6);
  int lane = threadIdx.x & 63;
  const u16* sr = states + (size_t)row * H_;
  float p = 0.f;
  #pragma unroll
  for (int j = 0; j < 16; j++){
    int c = j * 64 + lane;
    p += bf2f(sr[c]) * bf2f(Wg[c]);
  }
  #pragma unroll
  for (int o = 32; o; o >>= 1) p += __shfl_xor(p, o, 64);
  if (lane == 0) gws[row] = sigm(p + bf2f(bg[0]));
}

// ---------------- bitonic sort of (id<<11 | t) per batch ----------------
__global__ __launch_bounds__(1024) void sort_kernel(const int* __restrict__ ids, int* __restrict__ sorted)
{
  int b = blockIdx.x, tid = threadIdx.x;
  __shared__ int arr[S_];
  arr[tid] = (ids[b * S_ + tid] << 11) | tid;
  __syncthreads();
  for (int k = 2; k <= S_; k <<= 1){
    for (int j = k >> 1; j > 0; j >>= 1){
      int ixj = tid ^ j;
      if (ixj > tid){
        int a = arr[tid], c = arr[ixj];
        bool dir = (tid & k) == 0;
        if (dir ? (a > c) : (a < c)){ arr[tid] = c; arr[ixj] = a; }
      }
      __syncthreads();
    }
  }
  sorted[b * S_ + tid] = arr[tid];
}

// ---------------- attention: scores -> masked softmax -> gated = attn * g * mscale ----------------
__global__ __launch_bounds__(256) void attn_kernel(
    const u16* __restrict__ q, const u16* __restrict__ k,
    const float* __restrict__ gws, const float* __restrict__ scal,
    float* __restrict__ gated)
{
  int s = blockIdx.x, b = blockIdx.y;
  if (s == 0) return;
  int tid = threadIdx.x;
  __shared__ float qs[M_];
  __shared__ float rbm[4], rbs[4];
  if (tid < M_) qs[tid] = bf2f(q[((size_t)(b * S_ + s)) * M_ + tid]);
  __syncthreads();
  float myS[4];
  float lmax = -1e30f;
  #pragma unroll
  for (int r = 0; r < 4; r++){
    int t = tid + 256 * r;
    if (t < s){
      const uint4* kr = (const uint4*)(k + ((size_t)(b * S_ + t)) * M_);
      float d = 0.f;
      #pragma unroll
      for (int j = 0; j < 32; j++){
        uint4 kv = kr[j];
        u32 cc[4] = {kv.x, kv.y, kv.z, kv.w};
        #pragma unroll
        for (int e = 0; e < 4; e++)
          d += bflo(cc[e]) * qs[j * 8 + e * 2] + bfhi(cc[e]) * qs[j * 8 + e * 2 + 1];
      }
      d *= 0.0625f;                  // 1/sqrt(256)
      myS[r] = d;
      lmax = fmaxf(lmax, d);
    }
  }
  #pragma unroll
  for (int o = 32; o; o >>= 1) lmax = fmaxf(lmax, __shfl_xor(lmax, o, 64));
  if ((tid & 63) == 0) rbm[tid >> 6] = lmax;
  __syncthreads();
  float gmax = fmaxf(fmaxf(rbm[0], rbm[1]), fmaxf(rbm[2], rbm[3]));
  float lsum = 0.f;
  #pragma unroll
  for (int r = 0; r < 4; r++){
    int t = tid + 256 * r;
    if (t < s){ myS[r] = __expf(myS[r] - gmax); lsum += myS[r]; }
  }
  #pragma unroll
  for (int o = 32; o; o >>= 1) lsum += __shfl_xor(lsum, o, 64);
  if ((tid & 63) == 0) rbs[tid >> 6] = lsum;
  __syncthreads();
  float gsum = rbs[0] + rbs[1] + rbs[2] + rbs[3];
  float fac = gws[b * S_ + s] * scal[1] / gsum;
  float* grow = gated + ((size_t)(b * S_ + s)) * S_;
  #pragma unroll
  for (int r = 0; r < 4; r++){
    int t = tid + 256 * r;
    if (t < s) grow[t] = myS[r] * fac;
  }
}

// ---------------- scatter: out[b,s,ids[b,t]] += gated[b,s,t] (dup-merged, race-free, fp32) ----------------
__global__ __launch_bounds__(256) void scatter_kernel(
    const int* __restrict__ sorted, const float* __restrict__ gated,
    float* __restrict__ out)
{
  int gid = blockIdx.x * 256 + threadIdx.x;
  int e = gid & (S_ - 1);
  int row = gid >> 10;                  // b*S + s
  int s = row & (S_ - 1);
  int b = row >> 10;
  const int* sb = sorted + b * S_;
  int pk = sb[e];
  int v = pk >> 11;
  if (e > 0 && (sb[e - 1] >> 11) == v) return;   // only leaders
  const float* grow = gated + (size_t)row * S_;
  float sum = 0.f; bool any = false;
  for (int j = e; j < S_; j++){
    int pj = sb[j];
    if ((pj >> 11) != v) break;
    int t = pj & 2047;
    if (t < s){ sum += grow[t]; any = true; }
  }
  if (any){
    size_t off = (size_t)row * V_ + v;
    out[off] += sum;
  }
}

extern "C" void kernel_launch(void* const* d_in, const int* in_sizes, int n_in,
                              void* d_out, int out_size, void* d_ws, size_t ws_size,
                              hipStream_t stream)
{
  const int*  ids   = (const int*)d_in[0];
  const void* emb   = d_in[1];
  const void* W_ih  = d_in[2];
  const void* W_hh  = d_in[3];
  const void* b_ih  = d_in[4];
  const void* b_hh  = d_in[5];
  const void* Wq    = d_in[6];
  const void* bq    = d_in[7];
  const void* Wk    = d_in[8];
  const void* bk    = d_in[9];
  const void* Wg    = d_in[10];
  const void* bg    = d_in[11];
  const void* Whe   = d_in[12];
  const void* bhe   = d_in[13];
  const void* obias = d_in[14];
  const void* ms    = d_in[15];
  const void* smW   = d_in[16];
  const void* lam   = d_in[17];
  (void)in_sizes; (void)n_in; (void)out_size; (void)ws_size;

  char* ws = (char*)d_ws;
  int*   flag   = (int*)(ws + 0);
  float* scal   = (float*)(ws + 256);
  u64*   hslot  = (u64*)(ws + 512);
  u16*   c_emb  = (u16*)(ws + 33280);
  u16*   c_Wih  = (u16*)(ws + 32801280);
  u16*   c_Whh  = (u16*)(ws + 35947008);   // f16 content (GRU dot2 path)
  u16*   c_Wq   = (u16*)(ws + 42238464);
  u16*   c_Wk   = (u16*)(ws + 42762752);
  u16*   c_Wg   = (u16*)(ws + 43287040);
  u16*   c_Whe  = (u16*)(ws + 43289088);
  u16*   c_bih  = (u16*)(ws + 44337664);
  u16*   c_bhh  = (u16*)(ws + 44343808);
  u16*   c_bq   = (u16*)(ws + 44349952);
  u16*   c_bk   = (u16*)(ws + 44350464);
  u16*   c_bg   = (u16*)(ws + 44350976);
  u16*   c_bhe  = (u16*)(ws + 44351232);
  u16*   c_ob   = (u16*)(ws + 44352256);
  u16*   c_smW  = (u16*)(ws + 44416512);
  u16*   xs     = (u16*)(ws + 44416768);
  float* xg     = (float*)(ws + 46513920);
  u16*   states = (u16*)(ws + 71679744);
  u16*   hs     = (u16*)(ws + 75874048);
  u16*   qb     = (u16*)(ws + 77971200);
  u16*   kb     = (u16*)(ws + 79019776);
  float* gws    = (float*)(ws + 80068352);
  float* gated  = (float*)(ws + 80076544);
  int*   sorted = (int*)(ws + 88465152);
  float* out = (float*)d_out;

  hipMemsetAsync(hslot, 0, 32768, stream);   // h0 = 0 with tag 0
  detect_kernel<<<dim3(1), dim3(64), 0, stream>>>((const u32*)emb, flag, scal, lam, ms);

  #define CONV(src, dst, n) conv_kernel<<<dim3(((n)+255)/256), dim3(256), 0, stream>>>(src, dst, n, flag)
  CONV(emb,   c_emb, V_ * E_);
  CONV(W_ih,  c_Wih, 3 * H_ * E_);
  convh_kernel<<<dim3((3 * H_ * H_ + 255) / 256), dim3(256), 0, stream>>>(W_hh, c_Whh, 3 * H_ * H_, flag);
  CONV(Wq,    c_Wq,  M_ * H_);
  CONV(Wk,    c_Wk,  M_ * H_);
  CONV(Wg,    c_Wg,  H_);
  CONV(Whe,   c_Whe, E_ * H_);
  CONV(b_ih,  c_bih, 3 * H_);
  CONV(b_hh,  c_bhh, 3 * H_);
  CONV(bq,    c_bq,  M_);
  CONV(bk,    c_bk,  M_);
  CONV(bg,    c_bg,  1);
  CONV(bhe,   c_bhe, E_);
  CONV(obias, c_ob,  V_);
  CONV(smW,   c_smW, GC_);
  #undef CONV

  smear_kernel<<<dim3(B_ * S_), dim3(64), 0, stream>>>(ids, c_emb, c_smW, scal, xs);
  gemm_bt<false><<<dim3(3072 / 128, 2048 / 128), dim3(256), 0, stream>>>(xs, c_Wih, c_bih, (void*)xg, E_, 3072);
  gru_kernel<<<dim3(64), dim3(1024), 0, stream>>>(xg, c_Whh, c_bhh, hslot, states);
  gemm_bt<true><<<dim3(512 / 128, 16), dim3(256), 0, stream>>>(states, c_Whe, c_bhe, (void*)hs, H_, 512);
  gemm_bt<true><<<dim3(256 / 128, 16), dim3(256), 0, stream>>>(states, c_Wq, c_bq, (void*)qb, H_, 256);
  gemm_bt<true><<<dim3(256 / 128, 16), dim3(256), 0, stream>>>(states, c_Wk, c_bk, (void*)kb, H_, 256);
  gk_kernel<<<dim3(512), dim3(256), 0, stream>>>(states, c_Wg, c_bg, gws);
  sort_kernel<<<dim3(B_), dim3(1024), 0, stream>>>(ids, sorted);
  attn_kernel<<<dim3(S_, B_), dim3(256), 0, stream>>>(qb, kb, gws, scal, gated);
  gemm_bt<false><<<dim3(V_ / 128, 16), dim3(256), 0, stream>>>(hs, c_emb, c_ob, (void*)out, E_, V_);
  scatter_kernel<<<dim3(B_ * S_ * S_ / 256), dim3(256), 0, stream>>>(sorted, gated, out);
}